// Round 1
// baseline (619.237 us; speedup 1.0000x reference)
//
#include <hip/hip_runtime.h>

// Problem constants (fixed shapes from setup_inputs)
#define B 8
#define I 32
#define O 32
#define D 8
#define H 14
#define W 14
#define K 9
#define WK (W*K)              // 126
#define DSTRIDE (H*W*K)       // 1764
#define OSTRIDE (D*H*W*K)     // 14112
#define ISTRIDE (O*D*H*W*K)   // 451584
#define BSTRIDE ((size_t)I*ISTRIDE)
#define SUBSET 26             // ceil(0.8 * 32)

// One block per (b, o, h). 256 threads.
// Phase A (x16): stage 2 input-caps [2][D][126] into LDS (coalesced float2),
//   compute per-(w,k) norm over D, then K-weighted average -> ys[i][d][w].
// Phase B: ns (norm over D), v (consensus), losses, kth-smallest threshold
//   via stable-rank counting, masked weighted average -> out.
__global__ __launch_bounds__(256) void caps_route_kernel(const float* __restrict__ x,
                                                         float* __restrict__ out) {
    const int bid = blockIdx.x;
    const int h = bid % H;
    const int o = (bid / H) % O;
    const int b = bid / (H * O);
    const int t = threadIdx.x;

    __shared__ float xs[2][D][WK];   // staging: 2 input caps of [d][w*K+k]
    __shared__ float nk[2][WK];      // per-(w,k) norm over D
    __shared__ float ys[I][D][W];    // K-reduced capsules
    __shared__ float ns[I][W];       // norm over D of ys
    __shared__ float ls[I][W];       // losses
    __shared__ float vsh[D][W];      // consensus
    __shared__ float thr[W];         // kth-smallest loss per pixel

    const float* xb = x + (size_t)b * BSTRIDE + (size_t)o * OSTRIDE + (size_t)h * WK;

    for (int i0 = 0; i0 < I; i0 += 2) {
        // ---- stage 2 * D * 126 floats = 1008 float2 (all offsets even) ----
        const float2* src0 = (const float2*)(xb + (size_t)(i0    ) * ISTRIDE);
        const float2* src1 = (const float2*)(xb + (size_t)(i0 + 1) * ISTRIDE);
        #pragma unroll
        for (int it = 0; it < 4; ++it) {
            int f = t + it * 256;
            if (f < 1008) {
                int ii = f / 504;          // which input cap of the pair
                int r  = f - ii * 504;
                int d  = r / 63;           // 63 float2 per d-chunk
                int j  = r - d * 63;
                const float2* src = ii ? src1 : src0;
                float2 v2 = src[d * (DSTRIDE/2) + j];
                xs[ii][d][2*j]   = v2.x;
                xs[ii][d][2*j+1] = v2.y;
            }
        }
        __syncthreads();

        // ---- per-(w,k) norm over D ----
        if (t < 2 * WK) {
            int ii = t / WK, j = t - (t / WK) * WK;
            float s = 0.f;
            #pragma unroll
            for (int d = 0; d < D; ++d) { float v = xs[ii][d][j]; s += v * v; }
            nk[ii][j] = sqrtf(s);
        }
        __syncthreads();

        // ---- K-weighted average -> ys ----
        if (t < 2 * D * W) {
            int ii = t / (D * W);
            int r  = t - ii * (D * W);
            int d  = r / W, w = r - (r / W) * W;
            float num = 0.f, den = 0.f;
            #pragma unroll
            for (int k = 0; k < K; ++k) {
                float nv = nk[ii][w * K + k];
                num += nv * xs[ii][d][w * K + k];
                den += nv;
            }
            ys[i0 + ii][d][w] = num / den;
        }
        __syncthreads();   // also guards xs/nk reuse next iteration
    }

    // ---- ns[i][w] = ||ys[i][:][w]|| ----
    for (int f = t; f < I * W; f += 256) {
        int i = f / W, w = f - (f / W) * W;
        float s = 0.f;
        #pragma unroll
        for (int d = 0; d < D; ++d) { float v = ys[i][d][w]; s += v * v; }
        ns[i][w] = sqrtf(s);
    }
    __syncthreads();

    // ---- consensus v[d][w] ----
    if (t < D * W) {
        int d = t / W, w = t - (t / W) * W;
        float num = 0.f, den = 0.f;
        #pragma unroll
        for (int i = 0; i < I; ++i) {
            float nv = ns[i][w];
            num += nv * ys[i][d][w];
            den += nv;
        }
        vsh[d][w] = num / den;
    }
    __syncthreads();

    // ---- losses[i][w] = -sum_d v[d][w]*ys[i][d][w] ----
    for (int f = t; f < I * W; f += 256) {
        int i = f / W, w = f - (f / W) * W;
        float s = 0.f;
        #pragma unroll
        for (int d = 0; d < D; ++d) s += vsh[d][w] * ys[i][d][w];
        ls[i][w] = -s;
    }
    __syncthreads();

    // ---- kth smallest (k=SUBSET) via stable rank; matches jnp.sort[...,25] ----
    for (int f = t; f < I * W; f += 256) {
        int i = f / W, w = f - (f / W) * W;
        float li = ls[i][w];
        int rank = 0;
        #pragma unroll
        for (int j = 0; j < I; ++j) {
            float lj = ls[j][w];
            rank += (lj < li || (lj == li && j < i)) ? 1 : 0;
        }
        if (rank == SUBSET - 1) thr[w] = li;
    }
    __syncthreads();

    // ---- masked weighted average -> out[b][o][d][h][w] ----
    if (t < D * W) {
        int d = t / W, w = t - (t / W) * W;
        float tw = thr[w];
        float num = 0.f, den = 0.f;
        #pragma unroll
        for (int i = 0; i < I; ++i) {
            float m  = (ls[i][w] <= tw) ? 1.f : 0.f;
            float nv = m * ns[i][w];
            num += nv * ys[i][d][w];
            den += nv;
        }
        out[(((size_t)b * O + o) * D + d) * (H * W) + h * W + w] = num / den;
    }
}

extern "C" void kernel_launch(void* const* d_in, const int* in_sizes, int n_in,
                              void* d_out, int out_size, void* d_ws, size_t ws_size,
                              hipStream_t stream) {
    const float* x = (const float*)d_in[0];
    float* out = (float*)d_out;
    dim3 grid(B * O * H);   // 3584 blocks
    dim3 block(256);
    caps_route_kernel<<<grid, block, 0, stream>>>(x, out);
}

// Round 2
// 605.823 us; speedup vs baseline: 1.0221x; 1.0221x over previous
//
#include <hip/hip_runtime.h>

// Problem constants (fixed shapes from setup_inputs)
#define B 8
#define I 32
#define O 32
#define D 8
#define H 14
#define W 14
#define K 9
#define WK (W*K)              // 126
#define DSTRIDE (H*W*K)       // 1764
#define OSTRIDE (D*H*W*K)     // 14112
#define ISTRIDE (O*D*H*W*K)   // 451584
#define BSTRIDE ((size_t)I*ISTRIDE)
#define SUBSET 26             // ceil(0.8 * 32)

// One block per (b, o, h); 448 threads = one per (i, w) pair.
// Each thread loads its 72 floats x[b,i,o,0:8,h,w,0:9] into registers (all
// independent -> deep MLP, no barriers during load), computes per-k norms,
// K-weighted average ys[i][:][w] and its norm ns in registers, then 4 short
// LDS phases: consensus v, losses, kth-smallest threshold (stable rank),
// masked weighted average.
__global__ __launch_bounds__(448) void caps_route_kernel(const float* __restrict__ x,
                                                         float* __restrict__ out) {
    const int bid = blockIdx.x;
    const int h = bid % H;
    const int o = (bid / H) % O;
    const int b = bid / (H * O);
    const int t = threadIdx.x;
    const int i = t / W;      // 0..31
    const int w = t - i * W;  // 0..13

    __shared__ float ys[I][D][W];   // K-reduced capsules
    __shared__ float ns_s[I][W];    // norm over D of ys
    __shared__ float ls_s[I][W];    // losses
    __shared__ float vsh[D][W];     // consensus
    __shared__ float thr_s[W];      // kth-smallest loss per pixel

    const float* xp = x + (size_t)b * BSTRIDE + (size_t)i * ISTRIDE
                        + (size_t)o * OSTRIDE + (size_t)h * WK + (size_t)w * K;

    // ---- load 72 floats into registers (all loads independent) ----
    float xv[D][K];
    #pragma unroll
    for (int d = 0; d < D; ++d) {
        #pragma unroll
        for (int k = 0; k < K; ++k) {
            xv[d][k] = xp[d * DSTRIDE + k];
        }
    }

    // ---- per-k norm over D, then K-weighted average -> y[d], ns ----
    float nk[K];
    float den = 0.f;
    #pragma unroll
    for (int k = 0; k < K; ++k) {
        float s = 0.f;
        #pragma unroll
        for (int d = 0; d < D; ++d) { float v = xv[d][k]; s += v * v; }
        nk[k] = sqrtf(s);
        den += nk[k];
    }
    const float inv_den = 1.f / den;

    float y[D];
    float s2 = 0.f;
    #pragma unroll
    for (int d = 0; d < D; ++d) {
        float num = 0.f;
        #pragma unroll
        for (int k = 0; k < K; ++k) num += nk[k] * xv[d][k];
        y[d] = num * inv_den;
        ys[i][d][w] = y[d];
        s2 += y[d] * y[d];
    }
    const float nsv = sqrtf(s2);
    ns_s[i][w] = nsv;
    __syncthreads();

    // ---- consensus v[d][w] (112 threads) ----
    if (t < D * W) {
        const int d = t / W, w2 = t - (t / W) * W;
        float num = 0.f, dn = 0.f;
        #pragma unroll
        for (int j = 0; j < I; ++j) {
            float nv = ns_s[j][w2];
            num += nv * ys[j][d][w2];
            dn += nv;
        }
        vsh[d][w2] = num / dn;
    }
    __syncthreads();

    // ---- losses[i][w] = -sum_d v[d][w]*y[d] (all 448 threads, y in regs) ----
    float lv = 0.f;
    #pragma unroll
    for (int d = 0; d < D; ++d) lv += vsh[d][w] * y[d];
    lv = -lv;
    ls_s[i][w] = lv;
    __syncthreads();

    // ---- kth smallest (k=SUBSET) via stable rank; matches jnp.sort[...,25] ----
    int rank = 0;
    #pragma unroll
    for (int j = 0; j < I; ++j) {
        float lj = ls_s[j][w];
        rank += (lj < lv || (lj == lv && j < i)) ? 1 : 0;
    }
    if (rank == SUBSET - 1) thr_s[w] = lv;
    __syncthreads();

    // ---- masked weighted average -> out[b][o][d][h][w] (112 threads) ----
    if (t < D * W) {
        const int d = t / W, w2 = t - (t / W) * W;
        const float tw = thr_s[w2];
        float num = 0.f, dn = 0.f;
        #pragma unroll
        for (int j = 0; j < I; ++j) {
            float m  = (ls_s[j][w2] <= tw) ? 1.f : 0.f;
            float nv = m * ns_s[j][w2];
            num += nv * ys[j][d][w2];
            dn  += nv;
        }
        out[(((size_t)b * O + o) * D + d) * (H * W) + h * W + w2] = num / dn;
    }
}

extern "C" void kernel_launch(void* const* d_in, const int* in_sizes, int n_in,
                              void* d_out, int out_size, void* d_ws, size_t ws_size,
                              hipStream_t stream) {
    const float* x = (const float*)d_in[0];
    float* out = (float*)d_out;
    dim3 grid(B * O * H);   // 3584 blocks
    dim3 block(I * W);      // 448 threads = 7 waves
    caps_route_kernel<<<grid, block, 0, stream>>>(x, out);
}